// Round 1
// 724.442 us; speedup vs baseline: 1.0336x; 1.0336x over previous
//
#include <hip/hip_runtime.h>
#include <hip/hip_bf16.h>
#include <math.h>

#define D_ 512
#define K_ 8
#define L_ 64
#define Q_ 4096
#define C_ 4096
#define N_ (C_ * K_)   // 32768 rows of P viewed as [N][D]

typedef short short8 __attribute__((ext_vector_type(8)));
typedef float f32x4 __attribute__((ext_vector_type(4)));

static __device__ __forceinline__ void split2(float v, unsigned short& h, unsigned short& l) {
    __hip_bfloat16 hh = __float2bfloat16(v);
    float r = v - __bfloat162float(hh);
    __hip_bfloat16 ll = __float2bfloat16(r);
    h = *reinterpret_cast<unsigned short*>(&hh);
    l = *reinterpret_cast<unsigned short*>(&ll);
}

#define ASYNC_COPY16(gp, lp)                                                        \
    __builtin_amdgcn_global_load_lds((const __attribute__((address_space(1))) void*)(gp), \
                                     (__attribute__((address_space(3))) void*)(lp), \
                                     16, 0, 0)

// ---------------------------------------------------------------------------
// Prep kernels: transposes + fp32 -> bf16 hi/lo splits
// ---------------------------------------------------------------------------
__global__ void transpose_M_split(const float* __restrict__ M,
                                  unsigned short* __restrict__ Mh,
                                  unsigned short* __restrict__ Ml) {
    int idx = blockIdx.x * blockDim.x + threadIdx.x;   // over (K*D)*D, out [k*D+j][i]
    int i = idx & (D_ - 1);
    int n2 = idx >> 9;
    int j = n2 & (D_ - 1);
    int k = n2 >> 9;
    float v = M[((size_t)i * D_ + j) * K_ + k];
    split2(v, Mh[idx], Ml[idx]);
}

__global__ void split_f32(const float* __restrict__ x,
                          unsigned short* __restrict__ hi,
                          unsigned short* __restrict__ lo) {
    int i = blockIdx.x * blockDim.x + threadIdx.x;
    split2(x[i], hi[i], lo[i]);
}

__global__ void transpose_split_classT(const float* __restrict__ x,   // class [C][D]
                                       unsigned short* __restrict__ Th,
                                       unsigned short* __restrict__ Tl) {
    int idx = blockIdx.x * blockDim.x + threadIdx.x;   // out [d][c]
    int c = idx & (C_ - 1);
    int d = idx >> 12;
    float v = x[(size_t)c * D_ + d];
    split2(v, Th[idx], Tl[idx]);
}

// ---------------------------------------------------------------------------
// 8-phase 256x256 MFMA NT-GEMM core (T2+T3+T4+T5 stack), bf16x3.
// 512 threads = 8 waves (2M x 4N), per-wave output 128x64. BK=32.
// A and B (hi+lo) both staged via global_load_lds with pre-swizzled source
// (XOR on K-group, 2-way LDS conflicts = free), double-buffered: 128 KiB LDS.
// Per K-tile: 4 phases x 24 MFMA, 2 barriers/phase, ONE counted vmcnt(8)
// (tile t+2's 8 loads stay in flight across the barrier; never drained to 0).
// Stage of t+2 issues in phase 3, after all reads of that buffer completed.
// ---------------------------------------------------------------------------
#define OPS_ 8192            // shorts per operand plane (256 rows x 32)
#define BUFS_ (4 * OPS_)     // shorts per buffer (Ah, Al, Bh, Bl)

__device__ __forceinline__ void mfma_core8(
    const unsigned short* __restrict__ Agh, const unsigned short* __restrict__ Agl,
    const unsigned short* __restrict__ Bgh, const unsigned short* __restrict__ Bgl,
    const int lda, const int ldb, const int kd, const int m0, const int n0,
    unsigned short* Lds, f32x4 acc[8][4]) {
    const int tid = threadIdx.x;
    const int lane = tid & 63;
    const int wid = tid >> 6;
    const int fr = lane & 15;
    const int co = ((lane >> 4) ^ ((fr >> 1) & 3)) * 8;   // swizzled K-group (shorts)
    const int wm = (wid >> 2) * 128;                      // wave M offset
    const int wn = (wid & 3) * 64;                        // wave N offset
    const int nt = kd >> 5;                               // K-tiles of 32
    const int aoff = (wm + fr) * 32 + co;
    const int boff = (wn + fr) * 32 + co;

#define STAGE8(k0_, buf_)                                                              \
    {                                                                                  \
        _Pragma("unroll")                                                              \
        for (int h_ = 0; h_ < 2; ++h_) {                                               \
            const int i2_ = h_ * 512 + tid;                                            \
            const int r_ = i2_ >> 2;                                                   \
            const int cg_ = (i2_ & 3) ^ ((r_ >> 1) & 3);                               \
            unsigned short* lp_ = Lds + (buf_) * BUFS_ + (h_ * 512 + (tid & ~63)) * 8; \
            const size_t ga_ = (size_t)(m0 + r_) * lda + (k0_) + cg_ * 8;              \
            const size_t gb_ = (size_t)(n0 + r_) * ldb + (k0_) + cg_ * 8;              \
            ASYNC_COPY16(Agh + ga_, lp_);                                              \
            ASYNC_COPY16(Agl + ga_, lp_ + OPS_);                                       \
            ASYNC_COPY16(Bgh + gb_, lp_ + 2 * OPS_);                                   \
            ASYNC_COPY16(Bgl + gb_, lp_ + 3 * OPS_);                                   \
        }                                                                              \
    }

#define QUAD(MH, NH)                                                                         \
    _Pragma("unroll")                                                                        \
    for (int i_ = 0; i_ < 4; ++i_) {                                                         \
        _Pragma("unroll")                                                                    \
        for (int j_ = 0; j_ < 2; ++j_) {                                                     \
            f32x4& a_ = acc[(MH) * 4 + i_][(NH) * 2 + j_];                                   \
            a_ = __builtin_amdgcn_mfma_f32_16x16x32_bf16(ah[i_], bhv[(NH) * 2 + j_], a_, 0, 0, 0); \
            a_ = __builtin_amdgcn_mfma_f32_16x16x32_bf16(ah[i_], blv[(NH) * 2 + j_], a_, 0, 0, 0); \
            a_ = __builtin_amdgcn_mfma_f32_16x16x32_bf16(al[i_], bhv[(NH) * 2 + j_], a_, 0, 0, 0); \
        }                                                                                    \
    }

    // Prologue: stage tiles 0 and 1 (8 gload_lds each per wave), wait tile 0 only.
    STAGE8(0, 0)
    STAGE8(32, 1)
    asm volatile("s_waitcnt vmcnt(8)" ::: "memory");
    __builtin_amdgcn_sched_barrier(0);
    __builtin_amdgcn_s_barrier();

#pragma unroll 2
    for (int t = 0; t < nt; ++t) {
        const int cur = t & 1;
        const unsigned short* Lc = Lds + cur * BUFS_;
        short8 ah[4], al[4], bhv[4], blv[4];

        // ---- phase 0: read A-half0 (mi 0..3) + B ni 0..1; QUAD(0,0)
#pragma unroll
        for (int i = 0; i < 4; ++i) {
            ah[i] = *(const short8*)(Lc + aoff + i * 512);
            al[i] = *(const short8*)(Lc + OPS_ + aoff + i * 512);
        }
#pragma unroll
        for (int j = 0; j < 2; ++j) {
            bhv[j] = *(const short8*)(Lc + 2 * OPS_ + boff + j * 512);
            blv[j] = *(const short8*)(Lc + 3 * OPS_ + boff + j * 512);
        }
        __builtin_amdgcn_s_barrier();
        asm volatile("s_waitcnt lgkmcnt(0)" ::: "memory");
        __builtin_amdgcn_sched_barrier(0);
        __builtin_amdgcn_s_setprio(1);
        QUAD(0, 0)
        __builtin_amdgcn_s_setprio(0);
        __builtin_amdgcn_s_barrier();

        // ---- phase 1: read B ni 2..3; QUAD(0,1)
#pragma unroll
        for (int j = 2; j < 4; ++j) {
            bhv[j] = *(const short8*)(Lc + 2 * OPS_ + boff + j * 512);
            blv[j] = *(const short8*)(Lc + 3 * OPS_ + boff + j * 512);
        }
        __builtin_amdgcn_s_barrier();
        asm volatile("s_waitcnt lgkmcnt(0)" ::: "memory");
        __builtin_amdgcn_sched_barrier(0);
        __builtin_amdgcn_s_setprio(1);
        QUAD(0, 1)
        __builtin_amdgcn_s_setprio(0);
        __builtin_amdgcn_s_barrier();

        // ---- phase 2: read A-half1 (mi 4..7); QUAD(1,1)
#pragma unroll
        for (int i = 0; i < 4; ++i) {
            ah[i] = *(const short8*)(Lc + aoff + 2048 + i * 512);
            al[i] = *(const short8*)(Lc + OPS_ + aoff + 2048 + i * 512);
        }
        __builtin_amdgcn_s_barrier();
        asm volatile("s_waitcnt lgkmcnt(0)" ::: "memory");
        __builtin_amdgcn_sched_barrier(0);
        __builtin_amdgcn_s_setprio(1);
        QUAD(1, 1)
        __builtin_amdgcn_s_setprio(0);
        __builtin_amdgcn_s_barrier();

        // ---- phase 3: stage tile t+2 into buf[cur] (reads of it all done by
        // phase-2's trailing barrier); QUAD(1,0); counted vmcnt for tile t+1.
        if (t + 2 < nt) STAGE8((t + 2) * 32, cur)
        __builtin_amdgcn_s_barrier();
        __builtin_amdgcn_s_setprio(1);
        QUAD(1, 0)
        __builtin_amdgcn_s_setprio(0);
        if (t + 2 < nt) {
            asm volatile("s_waitcnt vmcnt(8)" ::: "memory");   // t+1 ready, t+2 in flight
        } else if (t + 1 < nt) {
            asm volatile("s_waitcnt vmcnt(0)" ::: "memory");   // last prefetched tile
        }
        __builtin_amdgcn_sched_barrier(0);
        __builtin_amdgcn_s_barrier();
    }
#undef STAGE8
#undef QUAD
}

// ---------------------------------------------------------------------------
// gemm_P: Ph/Pl[c][k*D+j] = split( sum_i class[c,i] * M[i,j,k] )
// ---------------------------------------------------------------------------
__launch_bounds__(512, 2)
__global__ void gemm_P_mfma8(const unsigned short* __restrict__ Chh,
                             const unsigned short* __restrict__ Cll,
                             const unsigned short* __restrict__ Mh,
                             const unsigned short* __restrict__ Ml,
                             unsigned short* __restrict__ Ph,
                             unsigned short* __restrict__ Pl) {
    __shared__ __attribute__((aligned(16))) unsigned short Lds[2 * BUFS_];
    f32x4 acc[8][4] = {};
    const int n0 = blockIdx.x * 256;   // over K*D
    const int c0 = blockIdx.y * 256;
    mfma_core8(Chh, Cll, Mh, Ml, D_, D_, D_, c0, n0, Lds, acc);
    const int lane = threadIdx.x & 63;
    const int wid = threadIdx.x >> 6;
    const int fr = lane & 15, fq = lane >> 4;
    const int wm = (wid >> 2) * 128, wn = (wid & 3) * 64;
#pragma unroll
    for (int mi = 0; mi < 8; ++mi)
#pragma unroll
        for (int ni = 0; ni < 4; ++ni)
#pragma unroll
            for (int r = 0; r < 4; ++r) {
                int c = c0 + wm + mi * 16 + fq * 4 + r;
                int n2 = n0 + wn + ni * 16 + fr;
                size_t o = (size_t)c * (K_ * D_) + n2;
                split2(acc[mi][ni][r], Ph[o], Pl[o]);
            }
}

// ---------------------------------------------------------------------------
// bilinear: other[q][c] = sb + sum_k sw[k]*relu( sum_j query[q,j]*P[c*8+k][j] )
// Grid is q-fastest: co-resident blocks share one B-panel (L2/L3 locality).
// ---------------------------------------------------------------------------
__launch_bounds__(512, 2)
__global__ void bilinear_mfma8(const unsigned short* __restrict__ Qh,
                               const unsigned short* __restrict__ Ql,
                               const unsigned short* __restrict__ Ph,
                               const unsigned short* __restrict__ Pl,
                               const float* __restrict__ sw,
                               const float* __restrict__ sb,
                               float* __restrict__ other) {
    __shared__ __attribute__((aligned(16))) unsigned short Lds[2 * BUFS_];
    f32x4 acc[8][4] = {};
    const int q0 = blockIdx.x * 256;   // q-fastest
    const int n0 = blockIdx.y * 256;   // over N = C*K
    mfma_core8(Qh, Ql, Ph, Pl, D_, D_, D_, q0, n0, Lds, acc);
    const int lane = threadIdx.x & 63;
    const int wid = threadIdx.x >> 6;
    const int fr = lane & 15, fq = lane >> 4;
    const int wm = (wid >> 2) * 128, wn = (wid & 3) * 64;
    const float wk = sw[lane & 7];
    const float bias = sb[0];
#pragma unroll
    for (int mi = 0; mi < 8; ++mi)
#pragma unroll
        for (int ni = 0; ni < 4; ++ni)
#pragma unroll
            for (int r = 0; r < 4; ++r) {
                float v = wk * fmaxf(acc[mi][ni][r], 0.f);
                v += __shfl_xor(v, 1);
                v += __shfl_xor(v, 2);
                v += __shfl_xor(v, 4);
                if ((lane & 7) == 0) {
                    int q = q0 + wm + mi * 16 + fq * 4 + r;
                    int c = (n0 + wn + ni * 16 + fr) >> 3;
                    other[(size_t)q * C_ + c] = v + bias;
                }
            }
}

// ---------------------------------------------------------------------------
// gemm_qf (split-K=8 over grid.z): qfp[z][q][d] = sum_{c in eighth} probs*classT
// ---------------------------------------------------------------------------
__launch_bounds__(512, 2)
__global__ void gemm_qf_mfma8(const unsigned short* __restrict__ Sh,
                              const unsigned short* __restrict__ Sl,
                              const unsigned short* __restrict__ Th,
                              const unsigned short* __restrict__ Tl,
                              float* __restrict__ qfp_base) {
    __shared__ __attribute__((aligned(16))) unsigned short Lds[2 * BUFS_];
    f32x4 acc[8][4] = {};
    const int n0 = blockIdx.x * 256;   // over D
    const int q0 = blockIdx.y * 256;
    const int zoff = blockIdx.z * (C_ / 8);
    float* qfp = qfp_base + (size_t)blockIdx.z * Q_ * D_;
    mfma_core8(Sh + zoff, Sl + zoff, Th + zoff, Tl + zoff,
               C_, C_, C_ / 8, q0, n0, Lds, acc);
    const int lane = threadIdx.x & 63;
    const int wid = threadIdx.x >> 6;
    const int fr = lane & 15, fq = lane >> 4;
    const int wm = (wid >> 2) * 128, wn = (wid & 3) * 64;
#pragma unroll
    for (int mi = 0; mi < 8; ++mi)
#pragma unroll
        for (int ni = 0; ni < 4; ++ni)
#pragma unroll
            for (int r = 0; r < 4; ++r) {
                int q = q0 + wm + mi * 16 + fq * 4 + r;
                int d = n0 + wn + ni * 16 + fr;
                qfp[(size_t)q * D_ + d] = acc[mi][ni][r];
            }
}

// ---------------------------------------------------------------------------
// Softmax over C per row; emits probs as split bf16 hi/lo. Row in registers.
// ---------------------------------------------------------------------------
__launch_bounds__(256)
__global__ void softmax_split(const float* __restrict__ other,
                              unsigned short* __restrict__ Sh,
                              unsigned short* __restrict__ Sl) {
    const int q = blockIdx.x;
    const float* row = other + (size_t)q * C_;
    const int tid = threadIdx.x;
    __shared__ float red[4];
    float v[16];
    float m = -1e30f;
#pragma unroll
    for (int it = 0; it < 16; ++it) {
        v[it] = row[tid + it * 256];
        m = fmaxf(m, v[it]);
    }
#pragma unroll
    for (int off = 32; off; off >>= 1) m = fmaxf(m, __shfl_down(m, off));
    if ((tid & 63) == 0) red[tid >> 6] = m;
    __syncthreads();
    m = fmaxf(fmaxf(red[0], red[1]), fmaxf(red[2], red[3]));
    __syncthreads();
    float s = 0.f;
#pragma unroll
    for (int it = 0; it < 16; ++it) {
        v[it] = __expf(v[it] - m);
        s += v[it];
    }
#pragma unroll
    for (int off = 32; off; off >>= 1) s += __shfl_down(s, off);
    if ((tid & 63) == 0) red[tid >> 6] = s;
    __syncthreads();
    const float inv = 1.f / (red[0] + red[1] + red[2] + red[3]);
#pragma unroll
    for (int it = 0; it < 16; ++it) {
        size_t o = (size_t)q * C_ + tid + it * 256;
        split2(v[it] * inv, Sh[o], Sl[o]);
    }
}

// ---------------------------------------------------------------------------
// hash[q][l] = tanh( sum_d (sum_z qfp[z] + query)[q][d]*hash_w[l][d] + hb[l] )
// ---------------------------------------------------------------------------
__launch_bounds__(256)
__global__ void hash_kernel(const float* __restrict__ qfp_base,
                            const float* __restrict__ Qv,
                            const float* __restrict__ hw,
                            const float* __restrict__ hb,
                            float* __restrict__ out) {
    __shared__ float sqf[4 * D_];
    const int q0 = blockIdx.x * 4;
    const int tid = threadIdx.x;
    {
        const float4* sq = (const float4*)&Qv[(size_t)q0 * D_];
        float4* dst = (float4*)sqf;
#pragma unroll
        for (int it = 0; it < 2; ++it) {
            int i = tid + it * 256;
            float4 o = sq[i];
#pragma unroll
            for (int z = 0; z < 8; ++z) {
                const float4 a =
                    ((const float4*)&qfp_base[(size_t)z * Q_ * D_ + (size_t)q0 * D_])[i];
                o.x += a.x; o.y += a.y; o.z += a.z; o.w += a.w;
            }
            dst[i] = o;
        }
    }
    __syncthreads();
    const int l = tid % L_;
    const int qi = tid / L_;
    float s = hb[l];
    const float* wrow = &hw[(size_t)l * D_];
    const float* xrow = &sqf[qi * D_];
#pragma unroll 4
    for (int d = 0; d < D_; d += 4) {
        float4 w4 = *(const float4*)&wrow[d];
        float4 x4 = *(const float4*)&xrow[d];
        s += x4.x * w4.x + x4.y * w4.y + x4.z * w4.z + x4.w * w4.w;
    }
    out[(size_t)(q0 + qi) * L_ + l] = tanhf(s);
}

// ---------------------------------------------------------------------------
extern "C" void kernel_launch(void* const* d_in, const int* in_sizes, int n_in,
                              void* d_out, int out_size, void* d_ws, size_t ws_size,
                              hipStream_t stream) {
    const float* class_v = (const float*)d_in[0];
    const float* query_v = (const float*)d_in[1];
    const float* M       = (const float*)d_in[2];
    const float* score_w = (const float*)d_in[3];
    const float* score_b = (const float*)d_in[4];
    const float* hash_w  = (const float*)d_in[5];
    const float* hash_b  = (const float*)d_in[6];
    float* out = (float*)d_out;

    // Workspace (142.6 MB, same footprint):
    //  [0,     33.5M)  Ph            -> Sh (probs hi) after softmax
    //  [33.5M, 67M)    Pl            -> Sl (probs lo)
    //  [67M,   134.2M) other (fp32 Q*C logits)
    //                  prep aliases (dead once bilinear writes other):
    //                    Mh/Ml at +0/+4.2M, Ch/Cl at +8.4M/+12.6M
    //                  post-softmax alias: qfp[8] at +0 (8 x 8.39M fp32 = 64MiB)
    //  [134.2M,142.6M) scratch: Qh/Ql (bf16)  -> Th/Tl (classT) after bilinear
    char* base = (char*)d_ws;
    unsigned short* Ph = (unsigned short*)base;
    unsigned short* Pl = (unsigned short*)(base + (size_t)33554432);
    char* oreg          = base + (size_t)67108864;
    float* other        = (float*)oreg;
    unsigned short* Mh  = (unsigned short*)oreg;
    unsigned short* Ml  = (unsigned short*)(oreg + (size_t)4194304);
    unsigned short* Chh = (unsigned short*)(oreg + (size_t)8388608);
    unsigned short* Cll = (unsigned short*)(oreg + (size_t)12582912);
    float* qfp          = (float*)oreg;
    char* scratch = base + (size_t)134217728;
    unsigned short* Qh = (unsigned short*)scratch;
    unsigned short* Ql = (unsigned short*)(scratch + (size_t)4194304);
    unsigned short* Th = (unsigned short*)scratch;
    unsigned short* Tl = (unsigned short*)(scratch + (size_t)4194304);
    unsigned short* Sh = Ph;
    unsigned short* Sl = Pl;

    transpose_M_split<<<(K_ * D_ * D_) / 256, 256, 0, stream>>>(M, Mh, Ml);
    split_f32<<<(C_ * D_) / 256, 256, 0, stream>>>(class_v, Chh, Cll);
    split_f32<<<(Q_ * D_) / 256, 256, 0, stream>>>(query_v, Qh, Ql);
    gemm_P_mfma8<<<dim3((K_ * D_) / 256, C_ / 256), 512, 0, stream>>>(Chh, Cll, Mh, Ml, Ph, Pl);
    bilinear_mfma8<<<dim3(Q_ / 256, N_ / 256), 512, 0, stream>>>(Qh, Ql, Ph, Pl,
                                                                 score_w, score_b, other);
    softmax_split<<<Q_, 256, 0, stream>>>(other, Sh, Sl);
    transpose_split_classT<<<(C_ * D_) / 256, 256, 0, stream>>>(class_v, Th, Tl);
    gemm_qf_mfma8<<<dim3(D_ / 256, Q_ / 256, 8), 512, 0, stream>>>(Sh, Sl, Th, Tl, qfp);
    hash_kernel<<<Q_ / 4, 256, 0, stream>>>(qfp, query_v, hash_w, hash_b, out);
}